// Round 7
// baseline (104.864 us; speedup 1.0000x reference)
//
#include <hip/hip_runtime.h>

typedef float f32x2 __attribute__((ext_vector_type(2)));
typedef float f32x4 __attribute__((ext_vector_type(4)));
typedef float f32x16 __attribute__((ext_vector_type(16)));
typedef _Float16 half8 __attribute__((ext_vector_type(8)));
typedef _Float16 half4 __attribute__((ext_vector_type(4)));
typedef unsigned int u32;
typedef u32 u32x4 __attribute__((ext_vector_type(4)));

#define S_LEN 2048
#define NHEAD 16
#define HDIM 64
#define BATCH 2
#define WINDOW 512
#define M2_FIX 5.770780163555852f   /* 4.0 * log2(e) */
#define LOG2E 1.4426950408889634f

#define GLDS16(gp, lp) __builtin_amdgcn_global_load_lds( \
    (const __attribute__((address_space(1))) void*)(gp), \
    (__attribute__((address_space(3))) void*)(lp), 16, 0, 0)

// ---------------- kernel 1: convert hs + W(q,k,v) f32 -> f16 ----------------
__global__ __launch_bounds__(256) void convert_kernel(
    const float4* __restrict__ hs, const float4* __restrict__ wq,
    const float4* __restrict__ wk, const float4* __restrict__ wv,
    _Float16* __restrict__ hsb, _Float16* __restrict__ wb) {
  int i = blockIdx.x * 256 + threadIdx.x;
  float4 v;
  _Float16* dst;
  if (i < 1048576) {
    v = hs[i];
    dst = hsb + (size_t)i * 4;
  } else {
    int j = i - 1048576;
    if (j < 262144) v = wq[j];
    else if (j < 524288) v = wk[j - 262144];
    else v = wv[j - 524288];
    dst = wb + (size_t)j * 4;
  }
  half4 o;
  o[0] = (_Float16)v.x; o[1] = (_Float16)v.y;
  o[2] = (_Float16)v.z; o[3] = (_Float16)v.w;
  *(half4*)dst = o;
}

// ---------------- kernel 2: QKV GEMM, m97 structure (unchanged) -------------
__global__ __launch_bounds__(256) void qkv_gemm(
    const _Float16* __restrict__ A, const _Float16* __restrict__ W,
    const float* __restrict__ bq, const float* __restrict__ bk,
    const float* __restrict__ bv,
    _Float16* __restrict__ Qb, _Float16* __restrict__ Kb, _Float16* __restrict__ Vb) {
  __shared__ _Float16 As[128][32];
  __shared__ _Float16 Bs[128][32];
  const int tid = threadIdx.x;
  const int wv = tid >> 6;
  const int lane = tid & 63;
  const int g = lane >> 4;
  const int c = lane & 15;
  int bid = blockIdx.x;
  bid = (bid & 7) * 96 + (bid >> 3);
  const int m0 = (bid & 31) * 128;
  const int n0 = (bid >> 5) * 128;
  const int wm = (wv & 1) * 64;
  const int wn = (wv >> 1) * 64;

  const int srow = lane >> 2;
  const int sslot = (lane & 3) ^ ((lane >> 4) & 3);
  const size_t aro0 = (size_t)(m0 + wv * 32 + srow) * 1024;
  const size_t aro1 = (size_t)(m0 + wv * 32 + 16 + srow) * 1024;
  const size_t bro0 = (size_t)(n0 + wv * 32 + srow) * 1024;
  const size_t bro1 = (size_t)(n0 + wv * 32 + 16 + srow) * 1024;
  char* asb = (char*)&As[0][0] + wv * 2048;
  char* bsb = (char*)&Bs[0][0] + wv * 2048;

  const int rcol = (g ^ ((c >> 2) & 3)) * 8;

  f32x4 acc[4][4];
#pragma unroll
  for (int i = 0; i < 4; ++i)
#pragma unroll
    for (int j = 0; j < 4; ++j) acc[i][j] = (f32x4){0.f, 0.f, 0.f, 0.f};

  for (int k0 = 0; k0 < 1024; k0 += 32) {
    const int ks = k0 + sslot * 8;
    GLDS16(A + aro0 + ks, asb);
    GLDS16(A + aro1 + ks, asb + 1024);
    GLDS16(W + bro0 + ks, bsb);
    GLDS16(W + bro1 + ks, bsb + 1024);
    __syncthreads();
    half8 af[4], bf[4];
#pragma unroll
    for (int mf = 0; mf < 4; ++mf)
      af[mf] = *(const half8*)&As[wm + mf * 16 + c][rcol];
#pragma unroll
    for (int nf = 0; nf < 4; ++nf)
      bf[nf] = *(const half8*)&Bs[wn + nf * 16 + c][rcol];
#pragma unroll
    for (int mf = 0; mf < 4; ++mf)
#pragma unroll
      for (int nf = 0; nf < 4; ++nf)
        acc[mf][nf] = __builtin_amdgcn_mfma_f32_16x16x32_f16(af[mf], bf[nf], acc[mf][nf], 0, 0, 0);
    __syncthreads();
  }

  const int kind = n0 >> 10;
  const int nb = (n0 + wn) & 1023;
  const int head = nb >> 6;
  const float* bias = kind == 0 ? bq : (kind == 1 ? bk : bv);
  _Float16* dst = kind == 0 ? Qb : (kind == 1 ? Kb : Vb);
  const float scl = kind == 0 ? (0.125f * LOG2E) : 1.0f;
#pragma unroll
  for (int nf = 0; nf < 4; ++nf) {
    const int d = nf * 16 + c;
    const float bsv = bias[nb + d];
#pragma unroll
    for (int mf = 0; mf < 4; ++mf) {
#pragma unroll
      for (int r = 0; r < 4; ++r) {
        const int t = m0 + wm + mf * 16 + g * 4 + r;
        const int bI = t >> 11;
        const int s = t & 2047;
        dst[(((size_t)(bI * NHEAD + head) * S_LEN) + s) * HDIM + d] =
            (_Float16)((acc[mf][nf][r] + bsv) * scl);
      }
    }
  }
}

// ---------------- kernel 3: V transpose  Vb[bh][s][d] -> Vt[bh][d][s] --------
__global__ __launch_bounds__(256) void transpose_v(const _Float16* __restrict__ Vb,
                                                   _Float16* __restrict__ Vt) {
  __shared__ _Float16 tile[64][72];
  const int bh = blockIdx.y;
  const int s0 = blockIdx.x * 64;
  const int row = threadIdx.x >> 2;
  const int col = (threadIdx.x & 3) * 16;
  const _Float16* src = Vb + ((size_t)bh * S_LEN + s0) * HDIM;
  *(half8*)&tile[row][col]     = *(const half8*)&src[row * HDIM + col];
  *(half8*)&tile[row][col + 8] = *(const half8*)&src[row * HDIM + col + 8];
  __syncthreads();
  _Float16* dst = Vt + ((size_t)bh * HDIM + row) * S_LEN + s0;
  half8 o0, o1;
#pragma unroll
  for (int q = 0; q < 8; ++q) o0[q] = tile[col + q][row];
#pragma unroll
  for (int q = 0; q < 8; ++q) o1[q] = tile[col + 8 + q][row];
  *(half8*)&dst[col]     = o0;
  *(half8*)&dst[col + 8] = o1;
}

// ---------------- kernel 4: windowed flash attention ------------------------
// 1 block (4 waves) per (bh, 32-q strip); wave w takes k-tiles t%4==w.
// Fixed-max softmax folded into MFMA C-init (-M2); native v_exp_f32;
// permlane32_swap P-exchange; masked tiles only on the causal diagonal.
__global__ __launch_bounds__(256) void attn_kernel(
    const _Float16* __restrict__ Qb, const _Float16* __restrict__ Kb,
    const _Float16* __restrict__ Vt, const float* __restrict__ amask,
    float* __restrict__ out) {
  __shared__ _Float16 obuf[4][32][72];
  __shared__ float lbuf[4][32];
  const int tid = threadIdx.x;
  const int w = tid >> 6;
  const int lane = tid & 63;
  const int q31 = lane & 31;
  const int h = lane >> 5;          // half-wave: k/d subgroup
  const int bid = blockIdx.x;
  const int bh = bid & 31;
  const int idx = 63 - (bid >> 5);  // longest strips launch first
  const int i0 = idx * 32;
  const int bI = bh >> 4;
  const int head = bh & 15;

  const _Float16* Qh = Qb + (size_t)bh * (S_LEN * HDIM);
  const _Float16* Kh = Kb + (size_t)bh * (S_LEN * HDIM);
  const _Float16* Vh = Vt + (size_t)bh * (HDIM * S_LEN);
  const float* am = amask + (size_t)bI * S_LEN;

  const int q = i0 + q31;
  const int hiq = (q <= WINDOW) ? q : (q - WINDOW - 1);
  const int last = i0 + 31;
  const int himax = (last <= WINDOW) ? last
                    : ((i0 <= WINDOW) ? WINDOW : (last - WINDOW - 1));
  const int hiq_min = (last <= WINDOW) ? i0
                      : ((i0 > WINDOW) ? (i0 - WINDOW - 1) : 0);
  const int ntiles = (himax >> 5) + 1;
  const int nfull = (hiq_min + 1) >> 5;   // tiles [0,nfull) need no masking
  const int lim = hiq - 4 * h;

  // Q B-frags (Q pre-scaled by 0.125*log2e)
  half8 qf[4];
#pragma unroll
  for (int ch = 0; ch < 4; ++ch)
    qf[ch] = *(const half8*)&Qh[(size_t)q * HDIM + ch * 16 + h * 8];

  f32x16 zero16, m2init;
#pragma unroll
  for (int r = 0; r < 16; ++r) { zero16[r] = 0.f; m2init[r] = -M2_FIX; }
  f32x16 oacc0 = zero16, oacc1 = zero16;
  f32x2 lp[4];
#pragma unroll
  for (int r = 0; r < 4; ++r) lp[r] = (f32x2){0.f, 0.f};

  auto computeTile = [&](half8 k0, half8 k1, half8 k2, half8 k3, int t)
      __attribute__((always_inline)) {
    const int j0 = t * 32;
    half8 vf0 = *(const half8*)&Vh[(size_t)q31 * S_LEN + j0 + h * 8];
    half8 vf1 = *(const half8*)&Vh[(size_t)q31 * S_LEN + j0 + 16 + h * 8];
    half8 vf2 = *(const half8*)&Vh[(size_t)(32 + q31) * S_LEN + j0 + h * 8];
    half8 vf3 = *(const half8*)&Vh[(size_t)(32 + q31) * S_LEN + j0 + 16 + h * 8];
    f32x4 amv[4];
#pragma unroll
    for (int s4 = 0; s4 < 4; ++s4)
      amv[s4] = *(const f32x4*)&am[j0 + 8 * s4 + 4 * h];

    __builtin_amdgcn_s_setprio(1);
    f32x16 st = __builtin_amdgcn_mfma_f32_32x32x16_f16(k0, qf[0], m2init, 0, 0, 0);
    st = __builtin_amdgcn_mfma_f32_32x32x16_f16(k1, qf[1], st, 0, 0, 0);
    st = __builtin_amdgcn_mfma_f32_32x32x16_f16(k2, qf[2], st, 0, 0, 0);
    st = __builtin_amdgcn_mfma_f32_32x32x16_f16(k3, qf[3], st, 0, 0, 0);
    __builtin_amdgcn_s_setprio(0);

    // z = st + am*log2e  (C-init already applied -M2); p = 2^z
    float p[16];
#pragma unroll
    for (int r = 0; r < 16; ++r)
      p[r] = __builtin_fmaf(amv[r >> 2][r & 3], LOG2E, st[r]);
    if (t >= nfull) {           // wave-uniform branch: diagonal/straddle only
      const int lm = lim - j0;
#pragma unroll
      for (int r = 0; r < 16; ++r) {
        const int off = (r & 3) + 8 * (r >> 2);
        p[r] = (off <= lm) ? p[r] : -3e38f;
      }
    }
#pragma unroll
    for (int r = 0; r < 16; ++r) p[r] = __builtin_amdgcn_exp2f(p[r]);
#pragma unroll
    for (int j = 0; j < 4; ++j) {
      lp[j] += (f32x2){p[2 * j], p[2 * j + 1]};
      lp[j] += (f32x2){p[8 + 2 * j], p[9 + 2 * j]};
    }

    // pack to f16 pairs, permlane32_swap exchange -> P^T B-frags
    u32 pk[8];
#pragma unroll
    for (int r = 0; r < 8; ++r) {
      auto c2 = __builtin_amdgcn_cvt_pkrtz(p[2 * r], p[2 * r + 1]);
      pk[r] = __builtin_bit_cast(u32, c2);
    }
    u32 a0 = pk[0], b0 = pk[2];
    u32 a1 = pk[1], b1 = pk[3];
    u32 a2 = pk[4], b2 = pk[6];
    u32 a3 = pk[5], b3 = pk[7];
    asm("v_permlane32_swap_b32 %0, %1" : "+v"(a0), "+v"(b0));
    asm("v_permlane32_swap_b32 %0, %1" : "+v"(a1), "+v"(b1));
    asm("v_permlane32_swap_b32 %0, %1" : "+v"(a2), "+v"(b2));
    asm("v_permlane32_swap_b32 %0, %1" : "+v"(a3), "+v"(b3));
    const half8 pf0 = __builtin_bit_cast(half8, (u32x4){a0, a1, b0, b1});
    const half8 pf1 = __builtin_bit_cast(half8, (u32x4){a2, a3, b2, b3});

    __builtin_amdgcn_s_setprio(1);
    oacc0 = __builtin_amdgcn_mfma_f32_32x32x16_f16(vf0, pf0, oacc0, 0, 0, 0);
    oacc0 = __builtin_amdgcn_mfma_f32_32x32x16_f16(vf1, pf1, oacc0, 0, 0, 0);
    oacc1 = __builtin_amdgcn_mfma_f32_32x32x16_f16(vf2, pf0, oacc1, 0, 0, 0);
    oacc1 = __builtin_amdgcn_mfma_f32_32x32x16_f16(vf3, pf1, oacc1, 0, 0, 0);
    __builtin_amdgcn_s_setprio(0);
  };

#define LOADK(d0, d1, d2, d3, jj)                                             \
  d0 = *(const half8*)&Kh[(size_t)((jj) + q31) * HDIM + h * 8];               \
  d1 = *(const half8*)&Kh[(size_t)((jj) + q31) * HDIM + 16 + h * 8];          \
  d2 = *(const half8*)&Kh[(size_t)((jj) + q31) * HDIM + 32 + h * 8];          \
  d3 = *(const half8*)&Kh[(size_t)((jj) + q31) * HDIM + 48 + h * 8];

  int t = w;
  if (t < ntiles) {
    half8 k0, k1, k2, k3;
    LOADK(k0, k1, k2, k3, t * 32);
    int tn = t + 4;
    while (tn < ntiles) {
      half8 n0, n1, n2, n3;
      LOADK(n0, n1, n2, n3, tn * 32);   // prefetch next tile's K
      computeTile(k0, k1, k2, k3, t);
      k0 = n0; k1 = n1; k2 = n2; k3 = n3;
      t = tn;
      tn += 4;
    }
    computeTile(k0, k1, k2, k3, t);
  }

  // per-wave lsum reduce; dump f16 partials to LDS
  f32x2 s2 = (lp[0] + lp[1]) + (lp[2] + lp[3]);
  float lw = s2[0] + s2[1];
  lw += __shfl_xor(lw, 32);
  if (h == 0) lbuf[w][q31] = lw;
#pragma unroll
  for (int j = 0; j < 4; ++j) {
    half4 h0, h1;
#pragma unroll
    for (int e = 0; e < 4; ++e) {
      h0[e] = (_Float16)oacc0[4 * j + e];
      h1[e] = (_Float16)oacc1[4 * j + e];
    }
    *(half4*)&obuf[w][q31][4 * h + 8 * j]      = h0;
    *(half4*)&obuf[w][q31][32 + 4 * h + 8 * j] = h1;
  }
  __syncthreads();

  // merge 4 wave-partials (f32 accumulate); normalize; store
  const int mq = tid >> 3;
  const int md = (tid & 7) * 8;
  const float lt = (lbuf[0][mq] + lbuf[1][mq]) + (lbuf[2][mq] + lbuf[3][mq]);
  float s[8];
  half8 p0 = *(const half8*)&obuf[0][mq][md];
#pragma unroll
  for (int e = 0; e < 8; ++e) s[e] = (float)p0[e];
#pragma unroll
  for (int w4 = 1; w4 < 4; ++w4) {
    half8 pw = *(const half8*)&obuf[w4][mq][md];
#pragma unroll
    for (int e = 0; e < 8; ++e) s[e] += (float)pw[e];
  }
  const float inv = 1.0f / lt;
  float4 s0, s1;
  s0.x = s[0] * inv; s0.y = s[1] * inv; s0.z = s[2] * inv; s0.w = s[3] * inv;
  s1.x = s[4] * inv; s1.y = s[5] * inv; s1.z = s[6] * inv; s1.w = s[7] * inv;
  float* op = out + ((size_t)(bI * S_LEN + i0 + mq)) * 1024 + head * 64 + md;
  *(float4*)op = s0;
  *(float4*)(op + 4) = s1;
}

// ---------------- launch --------------------------------------------------
extern "C" void kernel_launch(void* const* d_in, const int* in_sizes, int n_in,
                              void* d_out, int out_size, void* d_ws, size_t ws_size,
                              hipStream_t stream) {
  const float* hs = (const float*)d_in[0];
  const float* am = (const float*)d_in[1];
  const float* Wq = (const float*)d_in[2];
  const float* bq = (const float*)d_in[3];
  const float* Wk = (const float*)d_in[4];
  const float* bk = (const float*)d_in[5];
  const float* Wv = (const float*)d_in[6];
  const float* bv = (const float*)d_in[7];
  float* out = (float*)d_out;

  char* ws = (char*)d_ws;
  _Float16* hsb = (_Float16*)(ws);
  _Float16* wb  = (_Float16*)(ws + 8388608);
  _Float16* Qb  = (_Float16*)(ws + 14680064);
  _Float16* Kb  = (_Float16*)(ws + 23068672);
  _Float16* Vb  = (_Float16*)(ws + 31457280);
  _Float16* Vt  = (_Float16*)(ws + 39845888);

  convert_kernel<<<7168, 256, 0, stream>>>(
      (const float4*)hs, (const float4*)Wq, (const float4*)Wk, (const float4*)Wv, hsb, wb);
  qkv_gemm<<<768, 256, 0, stream>>>(hsb, wb, bq, bk, bv, Qb, Kb, Vb);
  transpose_v<<<dim3(32, 32), 256, 0, stream>>>(Vb, Vt);
  attn_kernel<<<2048, 256, 0, stream>>>(Qb, Kb, Vt, am, out);
}

// Round 8
// 88.668 us; speedup vs baseline: 1.1827x; 1.1827x over previous
//
#include <hip/hip_runtime.h>

typedef float f32x2 __attribute__((ext_vector_type(2)));
typedef float f32x4 __attribute__((ext_vector_type(4)));
typedef float f32x16 __attribute__((ext_vector_type(16)));
typedef _Float16 half8 __attribute__((ext_vector_type(8)));
typedef _Float16 half4 __attribute__((ext_vector_type(4)));
typedef unsigned int u32;
typedef u32 u32x4 __attribute__((ext_vector_type(4)));

#define S_LEN 2048
#define NHEAD 16
#define HDIM 64
#define BATCH 2
#define WINDOW 512
#define M2_FIX 5.770780163555852f   /* 4.0 * log2(e) */
#define LOG2E 1.4426950408889634f

#define GLDS16(gp, lp) __builtin_amdgcn_global_load_lds( \
    (const __attribute__((address_space(1))) void*)(gp), \
    (__attribute__((address_space(3))) void*)(lp), 16, 0, 0)

// Fragment-packed layouts (per bh = b*16+head, stride 131072 halfs = 64
// tiles x 2048):
//  Q/K tile t (s rows t*32..+31):  [ch(4)][lane(64)][j(8)]
//     lane = ((d>>3)&1)*32 + (s&31), ch = d>>4, j = d&7
//  V  tile t: [sub(4)][lane(64)][j(8)]  sub = (d>>5)*2 + ((s>>4)&1)
//     lane = ((s>>3)&1)*32 + (d&31), j = s&7
// Every attn fragment load is then base + lane*16B  (fully coalesced).

// ---------------- kernel 1: convert hs + W(q,k,v) f32 -> f16 ----------------
__global__ __launch_bounds__(256) void convert_kernel(
    const float4* __restrict__ hs, const float4* __restrict__ wq,
    const float4* __restrict__ wk, const float4* __restrict__ wv,
    _Float16* __restrict__ hsb, _Float16* __restrict__ wb) {
  int i = blockIdx.x * 256 + threadIdx.x;
  float4 v;
  _Float16* dst;
  if (i < 1048576) {
    v = hs[i];
    dst = hsb + (size_t)i * 4;
  } else {
    int j = i - 1048576;
    if (j < 262144) v = wq[j];
    else if (j < 524288) v = wk[j - 262144];
    else v = wv[j - 524288];
    dst = wb + (size_t)j * 4;
  }
  half4 o;
  o[0] = (_Float16)v.x; o[1] = (_Float16)v.y;
  o[2] = (_Float16)v.z; o[3] = (_Float16)v.w;
  *(half4*)dst = o;
}

// ---------------- kernel 2: QKV GEMM, m97 structure, frag-packed epilogue ---
__global__ __launch_bounds__(256) void qkv_gemm(
    const _Float16* __restrict__ A, const _Float16* __restrict__ W,
    const float* __restrict__ bq, const float* __restrict__ bk,
    const float* __restrict__ bv,
    _Float16* __restrict__ Qf, _Float16* __restrict__ Kf, _Float16* __restrict__ Vf) {
  __shared__ _Float16 As[128][32];
  __shared__ _Float16 Bs[128][32];
  const int tid = threadIdx.x;
  const int wv = tid >> 6;
  const int lane = tid & 63;
  const int g = lane >> 4;
  const int c = lane & 15;
  int bid = blockIdx.x;
  bid = (bid & 7) * 96 + (bid >> 3);
  const int m0 = (bid & 31) * 128;
  const int n0 = (bid >> 5) * 128;
  const int wm = (wv & 1) * 64;
  const int wn = (wv >> 1) * 64;

  const int srow_ = lane >> 2;
  const int sslot = (lane & 3) ^ ((lane >> 4) & 3);
  const size_t aro0 = (size_t)(m0 + wv * 32 + srow_) * 1024;
  const size_t aro1 = (size_t)(m0 + wv * 32 + 16 + srow_) * 1024;
  const size_t bro0 = (size_t)(n0 + wv * 32 + srow_) * 1024;
  const size_t bro1 = (size_t)(n0 + wv * 32 + 16 + srow_) * 1024;
  char* asb = (char*)&As[0][0] + wv * 2048;
  char* bsb = (char*)&Bs[0][0] + wv * 2048;

  const int rcol = (g ^ ((c >> 2) & 3)) * 8;

  f32x4 acc[4][4];
#pragma unroll
  for (int i = 0; i < 4; ++i)
#pragma unroll
    for (int j = 0; j < 4; ++j) acc[i][j] = (f32x4){0.f, 0.f, 0.f, 0.f};

  for (int k0 = 0; k0 < 1024; k0 += 32) {
    const int ks = k0 + sslot * 8;
    GLDS16(A + aro0 + ks, asb);
    GLDS16(A + aro1 + ks, asb + 1024);
    GLDS16(W + bro0 + ks, bsb);
    GLDS16(W + bro1 + ks, bsb + 1024);
    __syncthreads();
    half8 af[4], bf[4];
#pragma unroll
    for (int mf = 0; mf < 4; ++mf)
      af[mf] = *(const half8*)&As[wm + mf * 16 + c][rcol];
#pragma unroll
    for (int nf = 0; nf < 4; ++nf)
      bf[nf] = *(const half8*)&Bs[wn + nf * 16 + c][rcol];
#pragma unroll
    for (int mf = 0; mf < 4; ++mf)
#pragma unroll
      for (int nf = 0; nf < 4; ++nf)
        acc[mf][nf] = __builtin_amdgcn_mfma_f32_16x16x32_f16(af[mf], bf[nf], acc[mf][nf], 0, 0, 0);
    __syncthreads();
  }

  const int kind = n0 >> 10;                // 0=Q 1=K 2=V
  const int nb = (n0 + wn) & 1023;
  const int head = nb >> 6;
  const float* bias = kind == 0 ? bq : (kind == 1 ? bk : bv);

  if (kind < 2) {
    _Float16* dst = kind == 0 ? Qf : Kf;
    const float scl = kind == 0 ? (0.125f * LOG2E) : 1.0f;
#pragma unroll
    for (int nf = 0; nf < 4; ++nf) {
      const int d = nf * 16 + c;
      const float bsv = bias[nb + d];
      const size_t dbase = (size_t)(d >> 4) * 512 + ((d >> 3) & 1) * 256 + (d & 7);
#pragma unroll
      for (int mf = 0; mf < 4; ++mf) {
#pragma unroll
        for (int r = 0; r < 4; ++r) {
          const int srow = m0 + wm + mf * 16 + g * 4 + r;
          const int bI = srow >> 11;
          const int s = srow & 2047;
          dst[(size_t)(bI * NHEAD + head) * 131072 + (s >> 5) * 2048 +
              dbase + (s & 31) * 8] = (_Float16)((acc[mf][nf][r] + bsv) * scl);
        }
      }
    }
  } else {
#pragma unroll
    for (int nf = 0; nf < 4; ++nf) {
      const int d = nf * 16 + c;
      const float bsv = bias[nb + d];
#pragma unroll
      for (int mf = 0; mf < 4; ++mf) {
        const int S0 = m0 + wm + mf * 16 + g * 4;   // 4 consecutive s-values
        const int bI = S0 >> 11;
        const int s0 = S0 & 2047;
        half4 v4;
#pragma unroll
        for (int r = 0; r < 4; ++r) v4[r] = (_Float16)(acc[mf][nf][r] + bsv);
        const size_t off = (size_t)(bI * NHEAD + head) * 131072 +
            (s0 >> 5) * 2048 + ((d >> 5) * 2 + ((s0 >> 4) & 1)) * 512 +
            ((s0 >> 3) & 1) * 256 + (d & 31) * 8 + (s0 & 7);
        *(half4*)&Vf[off] = v4;
      }
    }
  }
}

// ---------------- kernel 3: windowed flash attention ------------------------
// 1 block (4 waves) per (bh, 32-q strip); wave w takes k-tiles t%4==w.
// All operands in frag-packed layouts -> every load is lane-contiguous.
// Fixed-max softmax folded into MFMA C-init; native v_exp_f32; permlane swap.
__global__ __launch_bounds__(256) void attn_kernel(
    const _Float16* __restrict__ Qf, const _Float16* __restrict__ Kf,
    const _Float16* __restrict__ Vf, const float* __restrict__ amask,
    float* __restrict__ out) {
  __shared__ _Float16 obuf[4][32][72];
  __shared__ float lbuf[4][32];
  const int tid = threadIdx.x;
  const int w = tid >> 6;
  const int lane = tid & 63;
  const int q31 = lane & 31;
  const int h = lane >> 5;
  const int bid = blockIdx.x;
  const int bh = bid & 31;
  const int idx = 63 - (bid >> 5);  // longest strips launch first
  const int i0 = idx * 32;
  const int bI = bh >> 4;
  const int head = bh & 15;

  const _Float16* Qh = Qf + (size_t)bh * 131072;
  const _Float16* Kh = Kf + (size_t)bh * 131072;
  const _Float16* Vh = Vf + (size_t)bh * 131072;
  const float* am = amask + (size_t)bI * S_LEN;

  const int q = i0 + q31;
  const int hiq = (q <= WINDOW) ? q : (q - WINDOW - 1);
  const int last = i0 + 31;
  const int himax = (last <= WINDOW) ? last
                    : ((i0 <= WINDOW) ? WINDOW : (last - WINDOW - 1));
  const int hiq_min = (last <= WINDOW) ? i0
                      : ((i0 > WINDOW) ? (i0 - WINDOW - 1) : 0);
  const int ntiles = (himax >> 5) + 1;
  const int nfull = (hiq_min + 1) >> 5;
  const int lim = hiq - 4 * h;

  // Q B-frags: coalesced lane*16B loads
  half8 qf[4];
#pragma unroll
  for (int ch = 0; ch < 4; ++ch)
    qf[ch] = *(const half8*)&Qh[(size_t)idx * 2048 + ch * 512 + lane * 8];

  f32x16 zero16, m2init;
#pragma unroll
  for (int r = 0; r < 16; ++r) { zero16[r] = 0.f; m2init[r] = -M2_FIX; }
  f32x16 oacc0 = zero16, oacc1 = zero16;
  f32x2 lp[4];
#pragma unroll
  for (int r = 0; r < 4; ++r) lp[r] = (f32x2){0.f, 0.f};

  auto computeTile = [&](half8 k0, half8 k1, half8 k2, half8 k3, int t)
      __attribute__((always_inline)) {
    const int j0 = t * 32;
    const _Float16* vt = Vh + (size_t)t * 2048 + lane * 8;
    half8 vf0 = *(const half8*)&vt[0];       // d 0..31,  k 0..15
    half8 vf1 = *(const half8*)&vt[512];     // d 0..31,  k 16..31
    half8 vf2 = *(const half8*)&vt[1024];    // d 32..63, k 0..15
    half8 vf3 = *(const half8*)&vt[1536];    // d 32..63, k 16..31
    f32x4 amv[4];
#pragma unroll
    for (int s4 = 0; s4 < 4; ++s4)
      amv[s4] = *(const f32x4*)&am[j0 + 8 * s4 + 4 * h];

    __builtin_amdgcn_s_setprio(1);
    f32x16 st = __builtin_amdgcn_mfma_f32_32x32x16_f16(k0, qf[0], m2init, 0, 0, 0);
    st = __builtin_amdgcn_mfma_f32_32x32x16_f16(k1, qf[1], st, 0, 0, 0);
    st = __builtin_amdgcn_mfma_f32_32x32x16_f16(k2, qf[2], st, 0, 0, 0);
    st = __builtin_amdgcn_mfma_f32_32x32x16_f16(k3, qf[3], st, 0, 0, 0);
    __builtin_amdgcn_s_setprio(0);

    float p[16];
#pragma unroll
    for (int r = 0; r < 16; ++r)
      p[r] = __builtin_fmaf(amv[r >> 2][r & 3], LOG2E, st[r]);
    if (t >= nfull) {
      const int lm = lim - j0;
#pragma unroll
      for (int r = 0; r < 16; ++r) {
        const int off = (r & 3) + 8 * (r >> 2);
        p[r] = (off <= lm) ? p[r] : -3e38f;
      }
    }
#pragma unroll
    for (int r = 0; r < 16; ++r) p[r] = __builtin_amdgcn_exp2f(p[r]);
#pragma unroll
    for (int j = 0; j < 4; ++j) {
      lp[j] += (f32x2){p[2 * j], p[2 * j + 1]};
      lp[j] += (f32x2){p[8 + 2 * j], p[9 + 2 * j]};
    }

    u32 pk[8];
#pragma unroll
    for (int r = 0; r < 8; ++r) {
      auto c2 = __builtin_amdgcn_cvt_pkrtz(p[2 * r], p[2 * r + 1]);
      pk[r] = __builtin_bit_cast(u32, c2);
    }
    u32 a0 = pk[0], b0 = pk[2];
    u32 a1 = pk[1], b1 = pk[3];
    u32 a2 = pk[4], b2 = pk[6];
    u32 a3 = pk[5], b3 = pk[7];
    asm("v_permlane32_swap_b32 %0, %1" : "+v"(a0), "+v"(b0));
    asm("v_permlane32_swap_b32 %0, %1" : "+v"(a1), "+v"(b1));
    asm("v_permlane32_swap_b32 %0, %1" : "+v"(a2), "+v"(b2));
    asm("v_permlane32_swap_b32 %0, %1" : "+v"(a3), "+v"(b3));
    const half8 pf0 = __builtin_bit_cast(half8, (u32x4){a0, a1, b0, b1});
    const half8 pf1 = __builtin_bit_cast(half8, (u32x4){a2, a3, b2, b3});

    __builtin_amdgcn_s_setprio(1);
    oacc0 = __builtin_amdgcn_mfma_f32_32x32x16_f16(vf0, pf0, oacc0, 0, 0, 0);
    oacc0 = __builtin_amdgcn_mfma_f32_32x32x16_f16(vf1, pf1, oacc0, 0, 0, 0);
    oacc1 = __builtin_amdgcn_mfma_f32_32x32x16_f16(vf2, pf0, oacc1, 0, 0, 0);
    oacc1 = __builtin_amdgcn_mfma_f32_32x32x16_f16(vf3, pf1, oacc1, 0, 0, 0);
    __builtin_amdgcn_s_setprio(0);
  };

#define LOADK(d0, d1, d2, d3, tt)                                        \
  {                                                                      \
    const _Float16* kt = Kh + (size_t)(tt) * 2048 + lane * 8;            \
    d0 = *(const half8*)&kt[0];                                          \
    d1 = *(const half8*)&kt[512];                                        \
    d2 = *(const half8*)&kt[1024];                                       \
    d3 = *(const half8*)&kt[1536];                                       \
  }

  int t = w;
  if (t < ntiles) {
    half8 k0, k1, k2, k3;
    LOADK(k0, k1, k2, k3, t);
    int tn = t + 4;
    while (tn < ntiles) {
      half8 n0, n1, n2, n3;
      LOADK(n0, n1, n2, n3, tn);   // prefetch next tile's K
      computeTile(k0, k1, k2, k3, t);
      k0 = n0; k1 = n1; k2 = n2; k3 = n3;
      t = tn;
      tn += 4;
    }
    computeTile(k0, k1, k2, k3, t);
  }

  f32x2 s2 = (lp[0] + lp[1]) + (lp[2] + lp[3]);
  float lw = s2[0] + s2[1];
  lw += __shfl_xor(lw, 32);
  if (h == 0) lbuf[w][q31] = lw;
#pragma unroll
  for (int j = 0; j < 4; ++j) {
    half4 h0, h1;
#pragma unroll
    for (int e = 0; e < 4; ++e) {
      h0[e] = (_Float16)oacc0[4 * j + e];
      h1[e] = (_Float16)oacc1[4 * j + e];
    }
    *(half4*)&obuf[w][q31][4 * h + 8 * j]      = h0;
    *(half4*)&obuf[w][q31][32 + 4 * h + 8 * j] = h1;
  }
  __syncthreads();

  const int mq = tid >> 3;
  const int md = (tid & 7) * 8;
  const float lt = (lbuf[0][mq] + lbuf[1][mq]) + (lbuf[2][mq] + lbuf[3][mq]);
  float s[8];
  half8 p0 = *(const half8*)&obuf[0][mq][md];
#pragma unroll
  for (int e = 0; e < 8; ++e) s[e] = (float)p0[e];
#pragma unroll
  for (int w4 = 1; w4 < 4; ++w4) {
    half8 pw = *(const half8*)&obuf[w4][mq][md];
#pragma unroll
    for (int e = 0; e < 8; ++e) s[e] += (float)pw[e];
  }
  const float inv = 1.0f / lt;
  float4 s0, s1;
  s0.x = s[0] * inv; s0.y = s[1] * inv; s0.z = s[2] * inv; s0.w = s[3] * inv;
  s1.x = s[4] * inv; s1.y = s[5] * inv; s1.z = s[6] * inv; s1.w = s[7] * inv;
  float* op = out + ((size_t)(bI * S_LEN + i0 + mq)) * 1024 + head * 64 + md;
  *(float4*)op = s0;
  *(float4*)(op + 4) = s1;
}

// ---------------- launch --------------------------------------------------
extern "C" void kernel_launch(void* const* d_in, const int* in_sizes, int n_in,
                              void* d_out, int out_size, void* d_ws, size_t ws_size,
                              hipStream_t stream) {
  const float* hs = (const float*)d_in[0];
  const float* am = (const float*)d_in[1];
  const float* Wq = (const float*)d_in[2];
  const float* bq = (const float*)d_in[3];
  const float* Wk = (const float*)d_in[4];
  const float* bk = (const float*)d_in[5];
  const float* Wv = (const float*)d_in[6];
  const float* bv = (const float*)d_in[7];
  float* out = (float*)d_out;

  char* ws = (char*)d_ws;
  _Float16* hsb = (_Float16*)(ws);
  _Float16* wb  = (_Float16*)(ws + 8388608);
  _Float16* Qf  = (_Float16*)(ws + 14680064);
  _Float16* Kf  = (_Float16*)(ws + 23068672);
  _Float16* Vf  = (_Float16*)(ws + 31457280);

  convert_kernel<<<7168, 256, 0, stream>>>(
      (const float4*)hs, (const float4*)Wq, (const float4*)Wk, (const float4*)Wv, hsb, wb);
  qkv_gemm<<<768, 256, 0, stream>>>(hsb, wb, bq, bk, bv, Qf, Kf, Vf);
  attn_kernel<<<2048, 256, 0, stream>>>(Qf, Kf, Vf, am, out);
}

// Round 9
// 78.522 us; speedup vs baseline: 1.3355x; 1.1292x over previous
//
#include <hip/hip_runtime.h>

typedef float f32x2 __attribute__((ext_vector_type(2)));
typedef float f32x4 __attribute__((ext_vector_type(4)));
typedef float f32x16 __attribute__((ext_vector_type(16)));
typedef _Float16 half8 __attribute__((ext_vector_type(8)));
typedef _Float16 half4 __attribute__((ext_vector_type(4)));
typedef unsigned int u32;
typedef u32 u32x4 __attribute__((ext_vector_type(4)));

#define S_LEN 2048
#define NHEAD 16
#define HDIM 64
#define BATCH 2
#define WINDOW 512
#define M2_FIX 5.770780163555852f   /* 4.0 * log2(e) */
#define LOG2E 1.4426950408889634f

#define GLDS16(gp, lp) __builtin_amdgcn_global_load_lds( \
    (const __attribute__((address_space(1))) void*)(gp), \
    (__attribute__((address_space(3))) void*)(lp), 16, 0, 0)

// Fragment-packed layouts (per bh = b*16+head, stride 131072 halfs):
//  Q/K tile t: [ch(4)][lane(64)][j(8)]  lane=((d>>3)&1)*32+(s&31), ch=d>>4, j=d&7
//  V   tile t: [sub(4)][lane(64)][j(8)] sub=(d>>5)*2+((s>>4)&1),
//                                       lane=((s>>3)&1)*32+(d&31), j=s&7

// ---------------- kernel 1: convert hs + W(q,k,v) f32 -> f16 ----------------
__global__ __launch_bounds__(256) void convert_kernel(
    const float4* __restrict__ hs, const float4* __restrict__ wq,
    const float4* __restrict__ wk, const float4* __restrict__ wv,
    _Float16* __restrict__ hsb, _Float16* __restrict__ wb) {
  int i = blockIdx.x * 256 + threadIdx.x;
  float4 v;
  _Float16* dst;
  if (i < 1048576) {
    v = hs[i];
    dst = hsb + (size_t)i * 4;
  } else {
    int j = i - 1048576;
    if (j < 262144) v = wq[j];
    else if (j < 524288) v = wk[j - 262144];
    else v = wv[j - 524288];
    dst = wb + (size_t)j * 4;
  }
  half4 o;
  o[0] = (_Float16)v.x; o[1] = (_Float16)v.y;
  o[2] = (_Float16)v.z; o[3] = (_Float16)v.w;
  *(half4*)dst = o;
}

// ---------------- kernel 2: QKV GEMM, BK=64, LDS-bounce epilogue ------------
__global__ __launch_bounds__(256) void qkv_gemm(
    const _Float16* __restrict__ A, const _Float16* __restrict__ W,
    const float* __restrict__ bq, const float* __restrict__ bk,
    const float* __restrict__ bv,
    _Float16* __restrict__ Qf, _Float16* __restrict__ Kf, _Float16* __restrict__ Vf) {
  __shared__ _Float16 sbuf[16384];   // 32KB: As[128][64] | Bs[128][64]; reused as ob[4][4096]
  const int tid = threadIdx.x;
  const int wv = tid >> 6;
  const int lane = tid & 63;
  const int g = lane >> 4;
  const int c = lane & 15;
  // XCD-locality: blocks dispatch round-robin over 8 XCDs; give each XCD 3
  // n-columns (24 = 8*3) so its B panels (3 x 256KB) stay L2-resident.
  const int b = blockIdx.x;
  const int slot = b >> 3;
  const int n0 = ((b & 7) * 3 + (slot >> 5)) * 128;
  const int m0 = (slot & 31) * 128;
  const int wm = (wv & 1) * 64;
  const int wn = (wv >> 1) * 64;

  // staging: wave stages A rows [wv*32,+32) and B rows [wv*32,+32)
  // LDS row = 64 halfs (128B); logical k-chunk l sits at slot l^(row&7).
  const int srow8 = lane >> 3;          // 0..7
  const int sslot = lane & 7;           // LDS slot this lane fills (linear dest)
  const int lsl = sslot ^ srow8;        // logical chunk -> pre-swizzled source
  const int rA = wv * 32 + srow8;
  const _Float16* aS = A + (size_t)(m0 + rA) * 1024 + lsl * 8;
  const _Float16* bS = W + (size_t)(n0 + rA) * 1024 + lsl * 8;
  _Float16* Asb = sbuf;
  _Float16* Bsb = sbuf + 8192;
  char* aDstU = (char*)(sbuf + (wv * 32) * 64);
  char* bDstU = (char*)(sbuf + 8192 + (wv * 32) * 64);

  f32x4 acc[4][4];
#pragma unroll
  for (int i = 0; i < 4; ++i)
#pragma unroll
    for (int j = 0; j < 4; ++j) acc[i][j] = (f32x4){0.f, 0.f, 0.f, 0.f};

  for (int k0 = 0; k0 < 1024; k0 += 64) {
#pragma unroll
    for (int grp = 0; grp < 4; ++grp) {
      GLDS16(aS + grp * 8192 + k0, aDstU + grp * 1024);
      GLDS16(bS + grp * 8192 + k0, bDstU + grp * 1024);
    }
    __syncthreads();
    half8 af[4][2];
#pragma unroll
    for (int mf = 0; mf < 4; ++mf) {
      const int row = wm + mf * 16 + c;
#pragma unroll
      for (int ch = 0; ch < 2; ++ch)
        af[mf][ch] = *(const half8*)&Asb[row * 64 + ((ch * 4 + g) ^ (c & 7)) * 8];
    }
#pragma unroll
    for (int nf = 0; nf < 4; ++nf) {
      const int row = wn + nf * 16 + c;
      half8 bf0 = *(const half8*)&Bsb[row * 64 + ((g) ^ (c & 7)) * 8];
      half8 bf1 = *(const half8*)&Bsb[row * 64 + ((4 + g) ^ (c & 7)) * 8];
#pragma unroll
      for (int mf = 0; mf < 4; ++mf) {
        acc[mf][nf] = __builtin_amdgcn_mfma_f32_16x16x32_f16(af[mf][0], bf0, acc[mf][nf], 0, 0, 0);
        acc[mf][nf] = __builtin_amdgcn_mfma_f32_16x16x32_f16(af[mf][1], bf1, acc[mf][nf], 0, 0, 0);
      }
    }
    __syncthreads();   // also guarantees all ds_reads done before bounce reuse
  }

  // ---- epilogue: scatter into per-wave LDS tile (final layout), then
  //      contiguous 1KB global stores. No barrier: wave-private region. ----
  const int kind = n0 >> 10;                // 0=Q 1=K 2=V
  const int nb = (n0 + wn) & 1023;
  const int head = nb >> 6;
  const float* bias = kind == 0 ? bq : (kind == 1 ? bk : bv);
  _Float16* dst = kind == 0 ? Qf : (kind == 1 ? Kf : Vf);
  _Float16* ob = sbuf + wv * 4096;

  if (kind < 2) {
    const float scl = kind == 0 ? (0.125f * LOG2E) : 1.0f;
#pragma unroll
    for (int nf = 0; nf < 4; ++nf) {
      const int d = nf * 16 + c;
      const float bsv = bias[nb + d];
      const int base = nf * 512 + ((c >> 3) & 1) * 256 + (c & 7);
#pragma unroll
      for (int mf = 0; mf < 4; ++mf) {
#pragma unroll
        for (int r = 0; r < 4; ++r) {
          ob[(mf >> 1) * 2048 + base + (mf & 1) * 128 + g * 32 + r * 8] =
              (_Float16)((acc[mf][nf][r] + bsv) * scl);
        }
      }
    }
  } else {
#pragma unroll
    for (int nf = 0; nf < 4; ++nf) {
      const int d = nf * 16 + c;
      const float bsv = bias[nb + d];
#pragma unroll
      for (int mf = 0; mf < 4; ++mf) {
        half4 v4;
#pragma unroll
        for (int r = 0; r < 4; ++r) v4[r] = (_Float16)(acc[mf][nf][r] + bsv);
        *(half4*)&ob[(mf >> 1) * 2048 + ((nf >> 1) * 2 + (mf & 1)) * 512 +
                     ((g >> 1) * 32 + (nf & 1) * 16 + c) * 8 + (g & 1) * 4] = v4;
      }
    }
  }

  // wave's 64 m-rows = 2 consecutive frag tiles = 8KB contiguous in dst
  const int bI = (m0 + wm) >> 11;
  const size_t gbase = (size_t)(bI * NHEAD + head) * 131072 +
                       (size_t)(((m0 + wm) & 2047) >> 5) * 2048;
#pragma unroll
  for (int i = 0; i < 8; ++i) {
    half8 v = *(const half8*)&ob[i * 512 + lane * 8];
    *(half8*)&dst[gbase + i * 512 + lane * 8] = v;
  }
}

// ---------------- kernel 3: windowed flash attention (unchanged) ------------
__global__ __launch_bounds__(256) void attn_kernel(
    const _Float16* __restrict__ Qf, const _Float16* __restrict__ Kf,
    const _Float16* __restrict__ Vf, const float* __restrict__ amask,
    float* __restrict__ out) {
  __shared__ _Float16 obuf[4][32][72];
  __shared__ float lbuf[4][32];
  const int tid = threadIdx.x;
  const int w = tid >> 6;
  const int lane = tid & 63;
  const int q31 = lane & 31;
  const int h = lane >> 5;
  const int bid = blockIdx.x;
  const int bh = bid & 31;
  const int idx = 63 - (bid >> 5);  // longest strips launch first
  const int i0 = idx * 32;
  const int bI = bh >> 4;
  const int head = bh & 15;

  const _Float16* Qh = Qf + (size_t)bh * 131072;
  const _Float16* Kh = Kf + (size_t)bh * 131072;
  const _Float16* Vh = Vf + (size_t)bh * 131072;
  const float* am = amask + (size_t)bI * S_LEN;

  const int q = i0 + q31;
  const int hiq = (q <= WINDOW) ? q : (q - WINDOW - 1);
  const int last = i0 + 31;
  const int himax = (last <= WINDOW) ? last
                    : ((i0 <= WINDOW) ? WINDOW : (last - WINDOW - 1));
  const int hiq_min = (last <= WINDOW) ? i0
                      : ((i0 > WINDOW) ? (i0 - WINDOW - 1) : 0);
  const int ntiles = (himax >> 5) + 1;
  const int nfull = (hiq_min + 1) >> 5;
  const int lim = hiq - 4 * h;

  half8 qf[4];
#pragma unroll
  for (int ch = 0; ch < 4; ++ch)
    qf[ch] = *(const half8*)&Qh[(size_t)idx * 2048 + ch * 512 + lane * 8];

  f32x16 zero16, m2init;
#pragma unroll
  for (int r = 0; r < 16; ++r) { zero16[r] = 0.f; m2init[r] = -M2_FIX; }
  f32x16 oacc0 = zero16, oacc1 = zero16;
  f32x2 lp[4];
#pragma unroll
  for (int r = 0; r < 4; ++r) lp[r] = (f32x2){0.f, 0.f};

  auto computeTile = [&](half8 k0, half8 k1, half8 k2, half8 k3, int t)
      __attribute__((always_inline)) {
    const int j0 = t * 32;
    const _Float16* vt = Vh + (size_t)t * 2048 + lane * 8;
    half8 vf0 = *(const half8*)&vt[0];
    half8 vf1 = *(const half8*)&vt[512];
    half8 vf2 = *(const half8*)&vt[1024];
    half8 vf3 = *(const half8*)&vt[1536];
    f32x4 amv[4];
#pragma unroll
    for (int s4 = 0; s4 < 4; ++s4)
      amv[s4] = *(const f32x4*)&am[j0 + 8 * s4 + 4 * h];

    __builtin_amdgcn_s_setprio(1);
    f32x16 st = __builtin_amdgcn_mfma_f32_32x32x16_f16(k0, qf[0], m2init, 0, 0, 0);
    st = __builtin_amdgcn_mfma_f32_32x32x16_f16(k1, qf[1], st, 0, 0, 0);
    st = __builtin_amdgcn_mfma_f32_32x32x16_f16(k2, qf[2], st, 0, 0, 0);
    st = __builtin_amdgcn_mfma_f32_32x32x16_f16(k3, qf[3], st, 0, 0, 0);
    __builtin_amdgcn_s_setprio(0);

    float p[16];
#pragma unroll
    for (int r = 0; r < 16; ++r)
      p[r] = __builtin_fmaf(amv[r >> 2][r & 3], LOG2E, st[r]);
    if (t >= nfull) {
      const int lm = lim - j0;
#pragma unroll
      for (int r = 0; r < 16; ++r) {
        const int off = (r & 3) + 8 * (r >> 2);
        p[r] = (off <= lm) ? p[r] : -3e38f;
      }
    }
#pragma unroll
    for (int r = 0; r < 16; ++r) p[r] = __builtin_amdgcn_exp2f(p[r]);
#pragma unroll
    for (int j = 0; j < 4; ++j) {
      lp[j] += (f32x2){p[2 * j], p[2 * j + 1]};
      lp[j] += (f32x2){p[8 + 2 * j], p[9 + 2 * j]};
    }

    u32 pk[8];
#pragma unroll
    for (int r = 0; r < 8; ++r) {
      auto c2 = __builtin_amdgcn_cvt_pkrtz(p[2 * r], p[2 * r + 1]);
      pk[r] = __builtin_bit_cast(u32, c2);
    }
    u32 a0 = pk[0], b0 = pk[2];
    u32 a1 = pk[1], b1 = pk[3];
    u32 a2 = pk[4], b2 = pk[6];
    u32 a3 = pk[5], b3 = pk[7];
    asm("v_permlane32_swap_b32 %0, %1" : "+v"(a0), "+v"(b0));
    asm("v_permlane32_swap_b32 %0, %1" : "+v"(a1), "+v"(b1));
    asm("v_permlane32_swap_b32 %0, %1" : "+v"(a2), "+v"(b2));
    asm("v_permlane32_swap_b32 %0, %1" : "+v"(a3), "+v"(b3));
    const half8 pf0 = __builtin_bit_cast(half8, (u32x4){a0, a1, b0, b1});
    const half8 pf1 = __builtin_bit_cast(half8, (u32x4){a2, a3, b2, b3});

    __builtin_amdgcn_s_setprio(1);
    oacc0 = __builtin_amdgcn_mfma_f32_32x32x16_f16(vf0, pf0, oacc0, 0, 0, 0);
    oacc0 = __builtin_amdgcn_mfma_f32_32x32x16_f16(vf1, pf1, oacc0, 0, 0, 0);
    oacc1 = __builtin_amdgcn_mfma_f32_32x32x16_f16(vf2, pf0, oacc1, 0, 0, 0);
    oacc1 = __builtin_amdgcn_mfma_f32_32x32x16_f16(vf3, pf1, oacc1, 0, 0, 0);
    __builtin_amdgcn_s_setprio(0);
  };

#define LOADK(d0, d1, d2, d3, tt)                                        \
  {                                                                      \
    const _Float16* kt = Kh + (size_t)(tt) * 2048 + lane * 8;            \
    d0 = *(const half8*)&kt[0];                                          \
    d1 = *(const half8*)&kt[512];                                        \
    d2 = *(const half8*)&kt[1024];                                       \
    d3 = *(const half8*)&kt[1536];                                       \
  }

  int t = w;
  if (t < ntiles) {
    half8 k0, k1, k2, k3;
    LOADK(k0, k1, k2, k3, t);
    int tn = t + 4;
    while (tn < ntiles) {
      half8 n0, n1, n2, n3;
      LOADK(n0, n1, n2, n3, tn);
      computeTile(k0, k1, k2, k3, t);
      k0 = n0; k1 = n1; k2 = n2; k3 = n3;
      t = tn;
      tn += 4;
    }
    computeTile(k0, k1, k2, k3, t);
  }

  f32x2 s2 = (lp[0] + lp[1]) + (lp[2] + lp[3]);
  float lw = s2[0] + s2[1];
  lw += __shfl_xor(lw, 32);
  if (h == 0) lbuf[w][q31] = lw;
#pragma unroll
  for (int j = 0; j < 4; ++j) {
    half4 h0, h1;
#pragma unroll
    for (int e = 0; e < 4; ++e) {
      h0[e] = (_Float16)oacc0[4 * j + e];
      h1[e] = (_Float16)oacc1[4 * j + e];
    }
    *(half4*)&obuf[w][q31][4 * h + 8 * j]      = h0;
    *(half4*)&obuf[w][q31][32 + 4 * h + 8 * j] = h1;
  }
  __syncthreads();

  const int mq = tid >> 3;
  const int md = (tid & 7) * 8;
  const float lt = (lbuf[0][mq] + lbuf[1][mq]) + (lbuf[2][mq] + lbuf[3][mq]);
  float s[8];
  half8 p0 = *(const half8*)&obuf[0][mq][md];
#pragma unroll
  for (int e = 0; e < 8; ++e) s[e] = (float)p0[e];
#pragma unroll
  for (int w4 = 1; w4 < 4; ++w4) {
    half8 pw = *(const half8*)&obuf[w4][mq][md];
#pragma unroll
    for (int e = 0; e < 8; ++e) s[e] += (float)pw[e];
  }
  const float inv = 1.0f / lt;
  float4 s0, s1;
  s0.x = s[0] * inv; s0.y = s[1] * inv; s0.z = s[2] * inv; s0.w = s[3] * inv;
  s1.x = s[4] * inv; s1.y = s[5] * inv; s1.z = s[6] * inv; s1.w = s[7] * inv;
  float* op = out + ((size_t)(bI * S_LEN + i0 + mq)) * 1024 + head * 64 + md;
  *(float4*)op = s0;
  *(float4*)(op + 4) = s1;
}

// ---------------- launch --------------------------------------------------
extern "C" void kernel_launch(void* const* d_in, const int* in_sizes, int n_in,
                              void* d_out, int out_size, void* d_ws, size_t ws_size,
                              hipStream_t stream) {
  const float* hs = (const float*)d_in[0];
  const float* am = (const float*)d_in[1];
  const float* Wq = (const float*)d_in[2];
  const float* bq = (const float*)d_in[3];
  const float* Wk = (const float*)d_in[4];
  const float* bk = (const float*)d_in[5];
  const float* Wv = (const float*)d_in[6];
  const float* bv = (const float*)d_in[7];
  float* out = (float*)d_out;

  char* ws = (char*)d_ws;
  _Float16* hsb = (_Float16*)(ws);
  _Float16* wb  = (_Float16*)(ws + 8388608);
  _Float16* Qf  = (_Float16*)(ws + 14680064);
  _Float16* Kf  = (_Float16*)(ws + 23068672);
  _Float16* Vf  = (_Float16*)(ws + 31457280);

  convert_kernel<<<7168, 256, 0, stream>>>(
      (const float4*)hs, (const float4*)Wq, (const float4*)Wk, (const float4*)Wv, hsb, wb);
  qkv_gemm<<<768, 256, 0, stream>>>(hsb, wb, bq, bk, bv, Qf, Kf, Vf);
  attn_kernel<<<2048, 256, 0, stream>>>(Qf, Kf, Vf, am, out);
}

// Round 10
// 77.099 us; speedup vs baseline: 1.3601x; 1.0185x over previous
//
#include <hip/hip_runtime.h>

typedef float f32x2 __attribute__((ext_vector_type(2)));
typedef float f32x4 __attribute__((ext_vector_type(4)));
typedef float f32x16 __attribute__((ext_vector_type(16)));
typedef _Float16 half8 __attribute__((ext_vector_type(8)));
typedef _Float16 half4 __attribute__((ext_vector_type(4)));
typedef unsigned int u32;
typedef u32 u32x4 __attribute__((ext_vector_type(4)));

#define S_LEN 2048
#define NHEAD 16
#define HDIM 64
#define BATCH 2
#define WINDOW 512
#define M2_FIX 5.770780163555852f   /* 4.0 * log2(e) */
#define LOG2E 1.4426950408889634f

#define GLDS16(gp, lp) __builtin_amdgcn_global_load_lds( \
    (const __attribute__((address_space(1))) void*)(gp), \
    (__attribute__((address_space(3))) void*)(lp), 16, 0, 0)

// Fragment-packed layouts (per bh = b*16+head, stride 131072 halfs):
//  Q/K tile t: [ch(4)][lane(64)][j(8)]  lane=((d>>3)&1)*32+(s&31), ch=d>>4, j=d&7
//  V   tile t: [sub(4)][lane(64)][j(8)] sub=(d>>5)*2+((s>>4)&1),
//                                       lane=((s>>3)&1)*32+(d&31), j=s&7

// ---------------- kernel 1: convert hs + W(q,k,v) f32 -> f16 ----------------
__global__ __launch_bounds__(256) void convert_kernel(
    const float4* __restrict__ hs, const float4* __restrict__ wq,
    const float4* __restrict__ wk, const float4* __restrict__ wv,
    _Float16* __restrict__ hsb, _Float16* __restrict__ wb) {
  int i = blockIdx.x * 256 + threadIdx.x;
  float4 v;
  _Float16* dst;
  if (i < 1048576) {
    v = hs[i];
    dst = hsb + (size_t)i * 4;
  } else {
    int j = i - 1048576;
    if (j < 262144) v = wq[j];
    else if (j < 524288) v = wk[j - 262144];
    else v = wv[j - 524288];
    dst = wb + (size_t)j * 4;
  }
  half4 o;
  o[0] = (_Float16)v.x; o[1] = (_Float16)v.y;
  o[2] = (_Float16)v.z; o[3] = (_Float16)v.w;
  *(half4*)dst = o;
}

// ---------------- kernel 2: QKV GEMM, BK=64, 2-phase dbuf pipeline ----------
__global__ __launch_bounds__(256) void qkv_gemm(
    const _Float16* __restrict__ A, const _Float16* __restrict__ W,
    const float* __restrict__ bq, const float* __restrict__ bk,
    const float* __restrict__ bv,
    _Float16* __restrict__ Qf, _Float16* __restrict__ Kf, _Float16* __restrict__ Vf) {
  __shared__ _Float16 sbuf[2][16384];   // 64KB: 2 x (As[128][64] | Bs[128][64])
  const int tid = threadIdx.x;
  const int wv = tid >> 6;
  const int lane = tid & 63;
  const int g = lane >> 4;
  const int c = lane & 15;
  // XCD-locality: blocks dispatch round-robin over 8 XCDs; each XCD owns 3
  // n-columns (24 = 8*3) so its B panels stay L2-resident.
  const int b = blockIdx.x;
  const int slot = b >> 3;
  const int n0 = ((b & 7) * 3 + (slot >> 5)) * 128;
  const int m0 = (slot & 31) * 128;
  const int wm = (wv & 1) * 64;
  const int wn = (wv >> 1) * 64;

  // staging: wave stages A rows [wv*32,+32) and B rows [wv*32,+32).
  // LDS row = 64 halfs (128B); logical k-chunk l sits at slot l^(row&7).
  const int srow8 = lane >> 3;          // 0..7
  const int sslot = lane & 7;           // LDS slot this lane fills (linear dest)
  const int lsl = sslot ^ srow8;        // pre-swizzled source chunk
  const int rA = wv * 32 + srow8;
  const _Float16* aS = A + (size_t)(m0 + rA) * 1024 + lsl * 8;
  const _Float16* bS = W + (size_t)(n0 + rA) * 1024 + lsl * 8;

  const int rcolA0 = wv * 32 * 64;      // wave's A staging base (halfs)

  f32x4 acc[4][4];
#pragma unroll
  for (int i = 0; i < 4; ++i)
#pragma unroll
    for (int j = 0; j < 4; ++j) acc[i][j] = (f32x4){0.f, 0.f, 0.f, 0.f};

  auto STAGE = [&](int bf_, int k0) __attribute__((always_inline)) {
    char* aD = (char*)&sbuf[bf_][rcolA0];
    char* bD = (char*)&sbuf[bf_][8192 + rcolA0];
#pragma unroll
    for (int grp = 0; grp < 4; ++grp) {
      GLDS16(aS + grp * 8192 + k0, aD + grp * 1024);
      GLDS16(bS + grp * 8192 + k0, bD + grp * 1024);
    }
  };

  STAGE(0, 0);
  __syncthreads();            // drains vmcnt: buf0 ready
  int cur = 0;

  for (int t = 0; t < 16; ++t) {
    if (t < 15) STAGE(cur ^ 1, (t + 1) * 64);   // issue next-tile loads FIRST
    const _Float16* Asb = &sbuf[cur][0];
    const _Float16* Bsb = &sbuf[cur][8192];
    half8 af[4][2];
#pragma unroll
    for (int mf = 0; mf < 4; ++mf) {
      const int row = wm + mf * 16 + c;
#pragma unroll
      for (int ch = 0; ch < 2; ++ch)
        af[mf][ch] = *(const half8*)&Asb[row * 64 + ((ch * 4 + g) ^ (c & 7)) * 8];
    }
#pragma unroll
    for (int nf = 0; nf < 4; ++nf) {
      const int row = wn + nf * 16 + c;
      half8 bf0 = *(const half8*)&Bsb[row * 64 + ((g) ^ (c & 7)) * 8];
      half8 bf1 = *(const half8*)&Bsb[row * 64 + ((4 + g) ^ (c & 7)) * 8];
#pragma unroll
      for (int mf = 0; mf < 4; ++mf) {
        acc[mf][nf] = __builtin_amdgcn_mfma_f32_16x16x32_f16(af[mf][0], bf0, acc[mf][nf], 0, 0, 0);
        acc[mf][nf] = __builtin_amdgcn_mfma_f32_16x16x32_f16(af[mf][1], bf1, acc[mf][nf], 0, 0, 0);
      }
    }
    __syncthreads();          // waits next-tile stage (mostly landed) + read-safety
    cur ^= 1;
  }

  // ---- epilogue: scatter into per-wave LDS tile (final layout), then
  //      contiguous 1KB global stores. Wave-private region of sbuf[0]. ----
  const int kind = n0 >> 10;                // 0=Q 1=K 2=V
  const int nb = (n0 + wn) & 1023;
  const int head = nb >> 6;
  const float* bias = kind == 0 ? bq : (kind == 1 ? bk : bv);
  _Float16* dst = kind == 0 ? Qf : (kind == 1 ? Kf : Vf);
  _Float16* ob = &sbuf[0][wv * 4096];

  if (kind < 2) {
    const float scl = kind == 0 ? (0.125f * LOG2E) : 1.0f;
#pragma unroll
    for (int nf = 0; nf < 4; ++nf) {
      const int d = nf * 16 + c;
      const float bsv = bias[nb + d];
      const int base = nf * 512 + ((c >> 3) & 1) * 256 + (c & 7);
#pragma unroll
      for (int mf = 0; mf < 4; ++mf) {
#pragma unroll
        for (int r = 0; r < 4; ++r) {
          ob[(mf >> 1) * 2048 + base + (mf & 1) * 128 + g * 32 + r * 8] =
              (_Float16)((acc[mf][nf][r] + bsv) * scl);
        }
      }
    }
  } else {
#pragma unroll
    for (int nf = 0; nf < 4; ++nf) {
      const int d = nf * 16 + c;
      const float bsv = bias[nb + d];
#pragma unroll
      for (int mf = 0; mf < 4; ++mf) {
        half4 v4;
#pragma unroll
        for (int r = 0; r < 4; ++r) v4[r] = (_Float16)(acc[mf][nf][r] + bsv);
        *(half4*)&ob[(mf >> 1) * 2048 + ((nf >> 1) * 2 + (mf & 1)) * 512 +
                     ((g >> 1) * 32 + (nf & 1) * 16 + c) * 8 + (g & 1) * 4] = v4;
      }
    }
  }

  // wave's 64 m-rows = 2 consecutive frag tiles = 8KB contiguous in dst
  const int bI = (m0 + wm) >> 11;
  const size_t gbase = (size_t)(bI * NHEAD + head) * 131072 +
                       (size_t)(((m0 + wm) & 2047) >> 5) * 2048;
#pragma unroll
  for (int i = 0; i < 8; ++i) {
    half8 v = *(const half8*)&ob[i * 512 + lane * 8];
    *(half8*)&dst[gbase + i * 512 + lane * 8] = v;
  }
}

// ---------------- kernel 3: windowed flash attention (unchanged) ------------
__global__ __launch_bounds__(256) void attn_kernel(
    const _Float16* __restrict__ Qf, const _Float16* __restrict__ Kf,
    const _Float16* __restrict__ Vf, const float* __restrict__ amask,
    float* __restrict__ out) {
  __shared__ _Float16 obuf[4][32][72];
  __shared__ float lbuf[4][32];
  const int tid = threadIdx.x;
  const int w = tid >> 6;
  const int lane = tid & 63;
  const int q31 = lane & 31;
  const int h = lane >> 5;
  const int bid = blockIdx.x;
  const int bh = bid & 31;
  const int idx = 63 - (bid >> 5);  // longest strips launch first
  const int i0 = idx * 32;
  const int bI = bh >> 4;
  const int head = bh & 15;

  const _Float16* Qh = Qf + (size_t)bh * 131072;
  const _Float16* Kh = Kf + (size_t)bh * 131072;
  const _Float16* Vh = Vf + (size_t)bh * 131072;
  const float* am = amask + (size_t)bI * S_LEN;

  const int q = i0 + q31;
  const int hiq = (q <= WINDOW) ? q : (q - WINDOW - 1);
  const int last = i0 + 31;
  const int himax = (last <= WINDOW) ? last
                    : ((i0 <= WINDOW) ? WINDOW : (last - WINDOW - 1));
  const int hiq_min = (last <= WINDOW) ? i0
                      : ((i0 > WINDOW) ? (i0 - WINDOW - 1) : 0);
  const int ntiles = (himax >> 5) + 1;
  const int nfull = (hiq_min + 1) >> 5;
  const int lim = hiq - 4 * h;

  half8 qf[4];
#pragma unroll
  for (int ch = 0; ch < 4; ++ch)
    qf[ch] = *(const half8*)&Qh[(size_t)idx * 2048 + ch * 512 + lane * 8];

  f32x16 zero16, m2init;
#pragma unroll
  for (int r = 0; r < 16; ++r) { zero16[r] = 0.f; m2init[r] = -M2_FIX; }
  f32x16 oacc0 = zero16, oacc1 = zero16;
  f32x2 lp[4];
#pragma unroll
  for (int r = 0; r < 4; ++r) lp[r] = (f32x2){0.f, 0.f};

  auto computeTile = [&](half8 k0, half8 k1, half8 k2, half8 k3, int t)
      __attribute__((always_inline)) {
    const int j0 = t * 32;
    const _Float16* vt = Vh + (size_t)t * 2048 + lane * 8;
    half8 vf0 = *(const half8*)&vt[0];
    half8 vf1 = *(const half8*)&vt[512];
    half8 vf2 = *(const half8*)&vt[1024];
    half8 vf3 = *(const half8*)&vt[1536];
    f32x4 amv[4];
#pragma unroll
    for (int s4 = 0; s4 < 4; ++s4)
      amv[s4] = *(const f32x4*)&am[j0 + 8 * s4 + 4 * h];

    __builtin_amdgcn_s_setprio(1);
    f32x16 st = __builtin_amdgcn_mfma_f32_32x32x16_f16(k0, qf[0], m2init, 0, 0, 0);
    st = __builtin_amdgcn_mfma_f32_32x32x16_f16(k1, qf[1], st, 0, 0, 0);
    st = __builtin_amdgcn_mfma_f32_32x32x16_f16(k2, qf[2], st, 0, 0, 0);
    st = __builtin_amdgcn_mfma_f32_32x32x16_f16(k3, qf[3], st, 0, 0, 0);
    __builtin_amdgcn_s_setprio(0);

    float p[16];
#pragma unroll
    for (int r = 0; r < 16; ++r)
      p[r] = __builtin_fmaf(amv[r >> 2][r & 3], LOG2E, st[r]);
    if (t >= nfull) {
      const int lm = lim - j0;
#pragma unroll
      for (int r = 0; r < 16; ++r) {
        const int off = (r & 3) + 8 * (r >> 2);
        p[r] = (off <= lm) ? p[r] : -3e38f;
      }
    }
#pragma unroll
    for (int r = 0; r < 16; ++r) p[r] = __builtin_amdgcn_exp2f(p[r]);
#pragma unroll
    for (int j = 0; j < 4; ++j) {
      lp[j] += (f32x2){p[2 * j], p[2 * j + 1]};
      lp[j] += (f32x2){p[8 + 2 * j], p[9 + 2 * j]};
    }

    u32 pk[8];
#pragma unroll
    for (int r = 0; r < 8; ++r) {
      auto c2 = __builtin_amdgcn_cvt_pkrtz(p[2 * r], p[2 * r + 1]);
      pk[r] = __builtin_bit_cast(u32, c2);
    }
    u32 a0 = pk[0], b0 = pk[2];
    u32 a1 = pk[1], b1 = pk[3];
    u32 a2 = pk[4], b2 = pk[6];
    u32 a3 = pk[5], b3 = pk[7];
    asm("v_permlane32_swap_b32 %0, %1" : "+v"(a0), "+v"(b0));
    asm("v_permlane32_swap_b32 %0, %1" : "+v"(a1), "+v"(b1));
    asm("v_permlane32_swap_b32 %0, %1" : "+v"(a2), "+v"(b2));
    asm("v_permlane32_swap_b32 %0, %1" : "+v"(a3), "+v"(b3));
    const half8 pf0 = __builtin_bit_cast(half8, (u32x4){a0, a1, b0, b1});
    const half8 pf1 = __builtin_bit_cast(half8, (u32x4){a2, a3, b2, b3});

    __builtin_amdgcn_s_setprio(1);
    oacc0 = __builtin_amdgcn_mfma_f32_32x32x16_f16(vf0, pf0, oacc0, 0, 0, 0);
    oacc0 = __builtin_amdgcn_mfma_f32_32x32x16_f16(vf1, pf1, oacc0, 0, 0, 0);
    oacc1 = __builtin_amdgcn_mfma_f32_32x32x16_f16(vf2, pf0, oacc1, 0, 0, 0);
    oacc1 = __builtin_amdgcn_mfma_f32_32x32x16_f16(vf3, pf1, oacc1, 0, 0, 0);
    __builtin_amdgcn_s_setprio(0);
  };

#define LOADK(d0, d1, d2, d3, tt)                                        \
  {                                                                      \
    const _Float16* kt = Kh + (size_t)(tt) * 2048 + lane * 8;            \
    d0 = *(const half8*)&kt[0];                                          \
    d1 = *(const half8*)&kt[512];                                        \
    d2 = *(const half8*)&kt[1024];                                       \
    d3 = *(const half8*)&kt[1536];                                       \
  }

  int t = w;
  if (t < ntiles) {
    half8 k0, k1, k2, k3;
    LOADK(k0, k1, k2, k3, t);
    int tn = t + 4;
    while (tn < ntiles) {
      half8 n0, n1, n2, n3;
      LOADK(n0, n1, n2, n3, tn);
      computeTile(k0, k1, k2, k3, t);
      k0 = n0; k1 = n1; k2 = n2; k3 = n3;
      t = tn;
      tn += 4;
    }
    computeTile(k0, k1, k2, k3, t);
  }

  f32x2 s2 = (lp[0] + lp[1]) + (lp[2] + lp[3]);
  float lw = s2[0] + s2[1];
  lw += __shfl_xor(lw, 32);
  if (h == 0) lbuf[w][q31] = lw;
#pragma unroll
  for (int j = 0; j < 4; ++j) {
    half4 h0, h1;
#pragma unroll
    for (int e = 0; e < 4; ++e) {
      h0[e] = (_Float16)oacc0[4 * j + e];
      h1[e] = (_Float16)oacc1[4 * j + e];
    }
    *(half4*)&obuf[w][q31][4 * h + 8 * j]      = h0;
    *(half4*)&obuf[w][q31][32 + 4 * h + 8 * j] = h1;
  }
  __syncthreads();

  const int mq = tid >> 3;
  const int md = (tid & 7) * 8;
  const float lt = (lbuf[0][mq] + lbuf[1][mq]) + (lbuf[2][mq] + lbuf[3][mq]);
  float s[8];
  half8 p0 = *(const half8*)&obuf[0][mq][md];
#pragma unroll
  for (int e = 0; e < 8; ++e) s[e] = (float)p0[e];
#pragma unroll
  for (int w4 = 1; w4 < 4; ++w4) {
    half8 pw = *(const half8*)&obuf[w4][mq][md];
#pragma unroll
    for (int e = 0; e < 8; ++e) s[e] += (float)pw[e];
  }
  const float inv = 1.0f / lt;
  float4 s0, s1;
  s0.x = s[0] * inv; s0.y = s[1] * inv; s0.z = s[2] * inv; s0.w = s[3] * inv;
  s1.x = s[4] * inv; s1.y = s[5] * inv; s1.z = s[6] * inv; s1.w = s[7] * inv;
  float* op = out + ((size_t)(bI * S_LEN + i0 + mq)) * 1024 + head * 64 + md;
  *(float4*)op = s0;
  *(float4*)(op + 4) = s1;
}

// ---------------- launch --------------------------------------------------
extern "C" void kernel_launch(void* const* d_in, const int* in_sizes, int n_in,
                              void* d_out, int out_size, void* d_ws, size_t ws_size,
                              hipStream_t stream) {
  const float* hs = (const float*)d_in[0];
  const float* am = (const float*)d_in[1];
  const float* Wq = (const float*)d_in[2];
  const float* bq = (const float*)d_in[3];
  const float* Wk = (const float*)d_in[4];
  const float* bk = (const float*)d_in[5];
  const float* Wv = (const float*)d_in[6];
  const float* bv = (const float*)d_in[7];
  float* out = (float*)d_out;

  char* ws = (char*)d_ws;
  _Float16* hsb = (_Float16*)(ws);
  _Float16* wb  = (_Float16*)(ws + 8388608);
  _Float16* Qf  = (_Float16*)(ws + 14680064);
  _Float16* Kf  = (_Float16*)(ws + 23068672);
  _Float16* Vf  = (_Float16*)(ws + 31457280);

  convert_kernel<<<7168, 256, 0, stream>>>(
      (const float4*)hs, (const float4*)Wq, (const float4*)Wk, (const float4*)Wv, hsb, wb);
  qkv_gemm<<<768, 256, 0, stream>>>(hsb, wb, bq, bk, bv, Qf, Kf, Vf);
  attn_kernel<<<2048, 256, 0, stream>>>(Qf, Kf, Vf, am, out);
}